// Round 7
// baseline (94.685 us; speedup 1.0000x reference)
//
#include <hip/hip_runtime.h>
#include <hip/hip_bf16.h>

namespace {
constexpr int Bv = 8;
constexpr int Nv = 2048;
constexpr int Dv = 256;
constexpr float SCALE = 0.1f;
constexpr float PSCALE = 256.0f;          // P quant scale (keeps fp8 in normal range)
constexpr float OSC = SCALE / PSCALE;     // epilogue un-scale
constexpr float LN_EPS = 1e-6f;
constexpr float NORM_EPS = 1e-12f;
}

typedef unsigned short u16;
typedef unsigned char u8;
typedef unsigned int u32;
typedef __attribute__((ext_vector_type(4))) float f32x4;

// global -> LDS direct DMA, 16B/lane. lds base wave-uniform; HW adds lane*16.
__device__ __forceinline__ void gll16(const void* g, void* l) {
    __builtin_amdgcn_global_load_lds(
        (__attribute__((address_space(1))) void*)(uintptr_t)g,
        (__attribute__((address_space(3))) void*)(uintptr_t)l, 16, 0, 0);
}
// pack 4 f32 -> 4 fp8 e4m3 bytes
__device__ __forceinline__ u32 pk4(float a, float b, float c, float d) {
    u32 w = __builtin_amdgcn_cvt_pk_fp8_f32(a, b, 0, false);
    return __builtin_amdgcn_cvt_pk_fp8_f32(c, d, w, true);
}
// Swizzled fp8 LDS frag read: rows are 64 B = 4 slots of 16B; slot' = slot^(row&3).
// Frag for MFMA kk: 8 bytes at k-offset kk*32 + kl*8.
__device__ __forceinline__ long lds_rd8(const void* base, int row, int kk, int kl) {
    const int slot = kk * 2 + (kl >> 1);
    return *(const long*)((const char*)base + row * 64 +
                          ((slot ^ (row & 3)) << 4) + ((kl & 1) << 3));
}

// ---------------------------------------------------------------------------
// 1) Fused prep: L2-normalize rows -> xn8 (fp8), transpose raw x -> xT8 (fp8),
//    zero lsum. Block = 64 rows x 256 cols, 512 threads (8 threads/row).
__global__ __launch_bounds__(512) void k_prepT(const float* __restrict__ x,
                                               u8* __restrict__ xn8,
                                               u8* __restrict__ xT8,
                                               float* __restrict__ lsum) {
    __shared__ u8 lt[64][272];   // raw-x fp8, [n_local][d], pad 272 (bank-even)
    const int b = blockIdx.x >> 5;
    const int n0 = (blockIdx.x & 31) * 64;
    const int t = threadIdx.x;
    const int r = t >> 3, c0 = (t & 7) * 32;
    if (blockIdx.x < 32) lsum[blockIdx.x * 512 + t] = 0.f;
    const float* xr = x + ((size_t)b * Nv + n0 + r) * Dv + c0;
    float4 v[8];
    float ss = 0.f;
#pragma unroll
    for (int i = 0; i < 8; ++i) {
        v[i] = ((const float4*)xr)[i];
        ss += v[i].x * v[i].x + v[i].y * v[i].y + v[i].z * v[i].z + v[i].w * v[i].w;
    }
#pragma unroll
    for (int m = 1; m < 8; m <<= 1) ss += __shfl_xor(ss, m, 64);
    const float inv = 1.0f / fmaxf(sqrtf(ss), NORM_EPS);
    u32 wn[8];
#pragma unroll
    for (int i = 0; i < 8; ++i) {
        wn[i] = pk4(v[i].x * inv, v[i].y * inv, v[i].z * inv, v[i].w * inv);
        *(u32*)&lt[r][c0 + i * 4] = pk4(v[i].x, v[i].y, v[i].z, v[i].w);
    }
    {
        uint4 o0 = {wn[0], wn[1], wn[2], wn[3]};
        uint4 o1 = {wn[4], wn[5], wn[6], wn[7]};
        u8* xnr = xn8 + ((size_t)b * Nv + n0 + r) * Dv + c0;
        *(uint4*)xnr = o0;
        *(uint4*)(xnr + 16) = o1;
    }
    __syncthreads();
    const int d = t >> 1, h = t & 1;
    u32 w2[8];
#pragma unroll
    for (int q = 0; q < 8; ++q) {
        const int nb = h * 32 + q * 4;
        w2[q] = (u32)lt[nb][d] | ((u32)lt[nb + 1][d] << 8) |
                ((u32)lt[nb + 2][d] << 16) | ((u32)lt[nb + 3][d] << 24);
    }
    uint4 p0 = {w2[0], w2[1], w2[2], w2[3]};
    uint4 p1 = {w2[4], w2[5], w2[6], w2[7]};
    u8* xtr = xT8 + ((size_t)b * Dv + d) * Nv + n0 + h * 32;
    *(uint4*)xtr = p0;
    *(uint4*)(xtr + 16) = p1;
}

// ---------------------------------------------------------------------------
// 2) E = exp(xn@xn^T - 1) fp8 (fp8 MFMA, 256x128 tile, BK=64, dbuf, 48KB LDS
//    -> 2 blocks/CU, 1024 balanced blocks). lsum += f32 row-sums. Tile stored
//    TRANSPOSED at mirrored position (E symmetric; all pairs computed).
__global__ __launch_bounds__(512, 4) void k_gemm1(const u8* __restrict__ xn8,
                                                  u8* __restrict__ E,
                                                  float* __restrict__ lsum) {
    __shared__ char smem[49152];   // A dbuf 32KB | B dbuf 16KB ; epi: 128x272 fp8
    const int wg = blockIdx.x;     // 1024: XCD owns one batch
    const int b = wg & 7;
    const int idx = wg >> 3;       // 0..127
    const int bi = idx >> 4, bj = idx & 15;   // 256-row block, 128-col block
    const int t = threadIdx.x;
    const int wave = t >> 6, lane = t & 63;
    const int wr = wave >> 1, wc = wave & 1;  // 4x2 waves, wave tile 64x64
    const int l15 = lane & 15, kl = lane >> 4;
    const u8* xb = xn8 + (size_t)b * Nv * Dv;

    auto stage = [&](int buf, int k0) {
#pragma unroll
        for (int c = 0; c < 2; ++c) {
            const int row = c * 128 + wave * 16 + (lane >> 2);
            const int sl = (lane & 3) ^ (row & 3);
            gll16(xb + (size_t)(bi * 256 + row) * Dv + k0 + sl * 16,
                  smem + buf * 16384 + c * 8192 + wave * 1024);
        }
        {
            const int row = wave * 16 + (lane >> 2);
            const int sl = (lane & 3) ^ (row & 3);
            gll16(xb + (size_t)(bj * 128 + row) * Dv + k0 + sl * 16,
                  smem + 32768 + buf * 8192 + wave * 1024);
        }
    };

    f32x4 acc[4][4] = {};
    stage(0, 0);
    __syncthreads();
    int cur = 0;
    for (int kt = 0; kt < 4; ++kt) {
        if (kt < 3) stage(cur ^ 1, (kt + 1) * 64);
        const char* pa = smem + cur * 16384;
        const char* pb = smem + 32768 + cur * 8192;
#pragma unroll
        for (int kk = 0; kk < 2; ++kk) {
            long bvv[4];
#pragma unroll
            for (int j = 0; j < 4; ++j)
                bvv[j] = lds_rd8(pb, wc * 64 + j * 16 + l15, kk, kl);
#pragma unroll
            for (int i = 0; i < 4; ++i) {
                long av = lds_rd8(pa, wr * 64 + i * 16 + l15, kk, kl);
#pragma unroll
                for (int j = 0; j < 4; ++j)
                    acc[i][j] = __builtin_amdgcn_mfma_f32_16x16x32_fp8_fp8(av, bvv[j], acc[i][j], 0, 0, 0);
            }
        }
        __syncthreads();
        cur ^= 1;
    }
    // epilogue: e=exp(s-1), rowsum atomics, fp8 pack -> LDS col-major [col][272]
    u8* lds8 = (u8*)smem;
#pragma unroll
    for (int i = 0; i < 4; ++i) {
        float rs[4] = {0.f, 0.f, 0.f, 0.f};
#pragma unroll
        for (int j = 0; j < 4; ++j) {
            const int col = wc * 64 + j * 16 + l15;
            const float e0 = __expf(acc[i][j][0] - 1.0f);
            const float e1 = __expf(acc[i][j][1] - 1.0f);
            const float e2 = __expf(acc[i][j][2] - 1.0f);
            const float e3 = __expf(acc[i][j][3] - 1.0f);
            rs[0] += e0; rs[1] += e1; rs[2] += e2; rs[3] += e3;
            *(u32*)&lds8[col * 272 + wr * 64 + i * 16 + kl * 4] = pk4(e0, e1, e2, e3);
        }
#pragma unroll
        for (int r = 0; r < 4; ++r) {
#pragma unroll
            for (int m = 1; m < 16; m <<= 1) rs[r] += __shfl_xor(rs[r], m, 64);
            if (l15 == 0)
                atomicAdd(&lsum[b * Nv + bi * 256 + wr * 64 + i * 16 + kl * 4 + r], rs[r]);
        }
    }
    __syncthreads();
    // transposed store at mirror: E[bj*128 + c][bi*256 + r], 256B rows.
    u8* Eb = E + (size_t)b * Nv * Nv;
    const int cc2 = t >> 2;            // 0..127
    const int off0 = (t & 3) * 64;
#pragma unroll
    for (int p = 0; p < 4; ++p) {
        const int off = off0 + p * 16;
        *(uint4*)&Eb[(size_t)(bj * 128 + cc2) * Nv + bi * 256 + off] =
            *(const uint4*)&lds8[cc2 * 272 + off];
    }
}

// ---------------------------------------------------------------------------
// 3) x_neg = P @ x, P[n,m] = E[n,m]*(1/l_n + 1/l_m)*PSCALE applied during fp8
//    A-staging (depth-3 E prefetch; 1/l cached in LDS). B = xT8 via gll16.
//    fp8 MFMA. Fused: out = LayerNorm(x - OSC*acc)*gamma + beta.
//    Block 64 rows x 256 cols, 8 waves (2x4), wave tile 32x64. 48KB LDS.
__global__ __launch_bounds__(512) void k_gemm2ln(const u8* __restrict__ E,
                                                 const float* __restrict__ lsum,
                                                 const u8* __restrict__ xT8,
                                                 const float* __restrict__ x,
                                                 const float* __restrict__ gamma,
                                                 const float* __restrict__ beta,
                                                 float* __restrict__ out) {
    __shared__ u8 Ps[2][64 * 64];     // 8 KB
    __shared__ u8 Xs[2][256 * 64];    // 32 KB
    __shared__ float rlv[Nv];         // 8 KB
    const int wg = blockIdx.x;        // 256: XCD owns one batch
    const int swz = (wg & 7) * 32 + (wg >> 3);
    const int b = swz >> 5, bi = swz & 31;
    const int t = threadIdx.x;
    const int wave = t >> 6, lane = t & 63;
    const int wr = wave >> 2, wc = wave & 3;
    const int l15 = lane & 15, kl = lane >> 4;
    const int s8 = t & 7;
    const int srow = t >> 3;          // A-tile row this thread stages (0..63)
    const float* lsb = lsum + (size_t)b * Nv;
    const u8* Erow = E + ((size_t)b * Nv + bi * 64 + srow) * Nv;
    const u8* xTb = xT8 + (size_t)b * Dv * Nv;
    const int pswb = srow * 64 + (((s8 >> 1) ^ (srow & 3)) << 4) + ((s8 & 1) << 3);
    float linv_n;

#pragma unroll
    for (int q = 0; q < 4; ++q) {
        const int m = q * 512 + t;
        rlv[m] = __builtin_amdgcn_rcpf(lsb[m]);
    }

    auto issueX = [&](int buf, int k0) {
#pragma unroll
        for (int c = 0; c < 2; ++c) {
            const int row = c * 128 + wave * 16 + (lane >> 2);
            const int sl = (lane & 3) ^ (row & 3);
            gll16(xTb + (size_t)row * Nv + k0 + sl * 16,
                  (char*)Xs[buf] + c * 8192 + wave * 1024);
        }
    };
    auto weightStore = [&](int buf, uint2 ev, int k0) {
        const float4 ra = *(const float4*)&rlv[k0 + s8 * 8];
        const float4 rb = *(const float4*)&rlv[k0 + s8 * 8 + 4];
        const float w0 = __builtin_amdgcn_cvt_f32_fp8(ev.x, 0) * (linv_n + ra.x) * PSCALE;
        const float w1 = __builtin_amdgcn_cvt_f32_fp8(ev.x, 1) * (linv_n + ra.y) * PSCALE;
        const float w2 = __builtin_amdgcn_cvt_f32_fp8(ev.x, 2) * (linv_n + ra.z) * PSCALE;
        const float w3 = __builtin_amdgcn_cvt_f32_fp8(ev.x, 3) * (linv_n + ra.w) * PSCALE;
        const float w4 = __builtin_amdgcn_cvt_f32_fp8(ev.y, 0) * (linv_n + rb.x) * PSCALE;
        const float w5 = __builtin_amdgcn_cvt_f32_fp8(ev.y, 1) * (linv_n + rb.y) * PSCALE;
        const float w6 = __builtin_amdgcn_cvt_f32_fp8(ev.y, 2) * (linv_n + rb.z) * PSCALE;
        const float w7 = __builtin_amdgcn_cvt_f32_fp8(ev.y, 3) * (linv_n + rb.w) * PSCALE;
        uint2 o;
        o.x = pk4(w0, w1, w2, w3);
        o.y = pk4(w4, w5, w6, w7);
        *(uint2*)&Ps[buf][pswb] = o;
    };

    issueX(0, 0);
    uint2 evB = *(const uint2*)(Erow + s8 * 8);
    __syncthreads();                  // rlv + Xs0 ready
    linv_n = rlv[bi * 64 + srow];
    weightStore(0, evB, 0);
    evB = *(const uint2*)(Erow + 64 + s8 * 8);
    uint2 evC = *(const uint2*)(Erow + 128 + s8 * 8);
    __syncthreads();                  // Ps0 ready
    f32x4 acc[2][4] = {};
    int cur = 0;
    for (int kt = 0; kt < 32; ++kt) {
        const int k1 = (kt + 1) * 64;
        if (kt < 31) issueX(cur ^ 1, k1);
#pragma unroll
        for (int kk = 0; kk < 2; ++kk) {
            long av0 = lds_rd8(Ps[cur], wr * 32 + l15, kk, kl);
            long av1 = lds_rd8(Ps[cur], wr * 32 + 16 + l15, kk, kl);
            long bvv[4];
#pragma unroll
            for (int j = 0; j < 4; ++j)
                bvv[j] = lds_rd8(Xs[cur], wc * 64 + j * 16 + l15, kk, kl);
#pragma unroll
            for (int j = 0; j < 4; ++j) {
                acc[0][j] = __builtin_amdgcn_mfma_f32_16x16x32_fp8_fp8(av0, bvv[j], acc[0][j], 0, 0, 0);
                acc[1][j] = __builtin_amdgcn_mfma_f32_16x16x32_fp8_fp8(av1, bvv[j], acc[1][j], 0, 0, 0);
            }
        }
        if (kt < 31) {
            weightStore(cur ^ 1, evB, k1);
            evB = evC;
            if (kt <= 28) evC = *(const uint2*)(Erow + (kt + 3) * 64 + s8 * 8);
        }
        __syncthreads();
        cur ^= 1;
    }
    // epilogue: v = x - OSC*acc, LN across the 4 column-waves.
    float (*red)[4][2] = (float (*)[4][2])(void*)Ps;   // overlay on dead Ps
    const float* xb = x + ((size_t)b * Nv + bi * 64) * Dv;
    float tv[2][4][4];
#pragma unroll
    for (int i = 0; i < 2; ++i) {
#pragma unroll
        for (int r = 0; r < 4; ++r) {
            const int rr = wr * 32 + i * 16 + kl * 4 + r;
            float s1 = 0.f, s2 = 0.f;
#pragma unroll
            for (int j = 0; j < 4; ++j) {
                const int cc = wc * 64 + j * 16 + l15;
                const float v = xb[(size_t)rr * Dv + cc] - OSC * acc[i][j][r];
                tv[i][j][r] = v;
                s1 += v; s2 += v * v;
            }
#pragma unroll
            for (int m = 1; m < 16; m <<= 1) {
                s1 += __shfl_xor(s1, m, 64);
                s2 += __shfl_xor(s2, m, 64);
            }
            if (l15 == 0) { red[rr][wc][0] = s1; red[rr][wc][1] = s2; }
        }
    }
    __syncthreads();
#pragma unroll
    for (int i = 0; i < 2; ++i) {
#pragma unroll
        for (int r = 0; r < 4; ++r) {
            const int rr = wr * 32 + i * 16 + kl * 4 + r;
            const float s1 = red[rr][0][0] + red[rr][1][0] + red[rr][2][0] + red[rr][3][0];
            const float s2 = red[rr][0][1] + red[rr][1][1] + red[rr][2][1] + red[rr][3][1];
            const float mu = s1 * (1.0f / Dv);
            const float var = s2 * (1.0f / Dv) - mu * mu;
            const float rstd = rsqrtf(var + LN_EPS);
#pragma unroll
            for (int j = 0; j < 4; ++j) {
                const int cc = wc * 64 + j * 16 + l15;
                out[((size_t)b * Nv + bi * 64 + rr) * Dv + cc] =
                    (tv[i][j][r] - mu) * rstd * gamma[cc] + beta[cc];
            }
        }
    }
}

// ---------------------------------------------------------------------------
extern "C" void kernel_launch(void* const* d_in, const int* in_sizes, int n_in,
                              void* d_out, int out_size, void* d_ws, size_t ws_size,
                              hipStream_t stream) {
    const float* x = (const float*)d_in[0];
    const float* gamma = (const float*)d_in[1];
    const float* beta = (const float*)d_in[2];
    float* out = (float*)d_out;
    char* ws = (char*)d_ws;
    u8* xn8 = (u8*)ws;                        // 4.2 MB
    u8* xT8 = (u8*)(ws + 4194304);            // 4.2 MB
    float* lsum = (float*)(ws + 8388608);     // 64 KB
    u8* E = (u8*)(ws + 8454144);              // 33.5 MB (fp8)

    k_prepT<<<Bv * (Nv / 64), 512, 0, stream>>>(x, xn8, xT8, lsum);
    k_gemm1<<<Bv * (Nv / 256) * (Nv / 128), 512, 0, stream>>>(xn8, E, lsum);
    k_gemm2ln<<<Bv * (Nv / 64), 512, 0, stream>>>(E, lsum, xT8, x, gamma, beta, out);
}

// Round 8
// 88.136 us; speedup vs baseline: 1.0743x; 1.0743x over previous
//
#include <hip/hip_runtime.h>

namespace {
constexpr int Bv = 8;
constexpr int Nv = 2048;
constexpr int Dv = 256;
constexpr float SCALE = 0.1f;
constexpr float PSCALE = 256.0f;          // P quant scale (fp8 normal range)
constexpr float OSC = SCALE / PSCALE;     // epilogue un-scale
constexpr float LN_EPS = 1e-6f;
constexpr float NORM_EPS = 1e-12f;
}

typedef unsigned char u8;
typedef unsigned int u32;
typedef __attribute__((ext_vector_type(4))) float f32x4;

// pack 4 f32 -> 4 fp8 e4m3 bytes
__device__ __forceinline__ u32 pk4(float a, float b, float c, float d) {
    u32 w = __builtin_amdgcn_cvt_pk_fp8_f32(a, b, 0, false);
    return __builtin_amdgcn_cvt_pk_fp8_f32(c, d, w, true);
}

// ---------------------------------------------------------------------------
// 1) Fused prep. Outputs (both fp8, FRAGMENT-ORDERED for coalesced direct
//    MFMA-frag loads):  xnf[g=n/16][c=d/8][l=n%16][8B]  (L2-normalized rows)
//                       xTf[g=d/16][c=n/8][l=d%16][8B]  (raw x, transposed)
//    Block = 64 n-rows x 256 d. Also zeros lsum.
__global__ __launch_bounds__(512) void k_prepT(const float* __restrict__ x,
                                               u8* __restrict__ xnf,
                                               u8* __restrict__ xTf,
                                               float* __restrict__ lsum) {
    __shared__ u8 lt[64][272];   // raw-x fp8 [n_local][d]
    const int b = blockIdx.x >> 5;
    const int n0 = (blockIdx.x & 31) * 64;
    const int t = threadIdx.x;
    const int r = t >> 3, c0 = (t & 7) * 32;
    if (blockIdx.x < 32) lsum[blockIdx.x * 512 + t] = 0.f;
    const float* xr = x + ((size_t)b * Nv + n0 + r) * Dv + c0;
    float4 v[8];
    float ss = 0.f;
#pragma unroll
    for (int i = 0; i < 8; ++i) {
        v[i] = ((const float4*)xr)[i];
        ss += v[i].x * v[i].x + v[i].y * v[i].y + v[i].z * v[i].z + v[i].w * v[i].w;
    }
#pragma unroll
    for (int m = 1; m < 8; m <<= 1) ss += __shfl_xor(ss, m, 64);
    const float inv = 1.0f / fmaxf(sqrtf(ss), NORM_EPS);
    u32 wn[8];
#pragma unroll
    for (int i = 0; i < 8; ++i) {
        wn[i] = pk4(v[i].x * inv, v[i].y * inv, v[i].z * inv, v[i].w * inv);
        *(u32*)&lt[r][c0 + i * 4] = pk4(v[i].x, v[i].y, v[i].z, v[i].w);
    }
    // xnf writes: g = n/16, l = n%16; this thread covers c-units (t&7)*4+q
    {
        u8* xnb = xnf + (size_t)b * 524288;
        const int g = (n0 + r) >> 4, l = r & 15;
#pragma unroll
        for (int q = 0; q < 4; ++q) {
            uint2 o = {wn[2 * q], wn[2 * q + 1]};
            *(uint2*)&xnb[g * 4096 + ((t & 7) * 4 + q) * 128 + l * 8] = o;
        }
    }
    __syncthreads();
    // xTf writes: thread handles d = t>>1, n-half h = t&1 (32 n = 4 c-units)
    {
        u8* xtb = xTf + (size_t)b * 524288;
        const int d = t >> 1, h = t & 1;
        const int g = d >> 4, l = d & 15;
#pragma unroll
        for (int q = 0; q < 4; ++q) {
            const int nb = h * 32 + q * 8;
            u32 lo = (u32)lt[nb][d] | ((u32)lt[nb + 1][d] << 8) |
                     ((u32)lt[nb + 2][d] << 16) | ((u32)lt[nb + 3][d] << 24);
            u32 hi = (u32)lt[nb + 4][d] | ((u32)lt[nb + 5][d] << 8) |
                     ((u32)lt[nb + 6][d] << 16) | ((u32)lt[nb + 7][d] << 24);
            uint2 o = {lo, hi};
            const int c = (n0 >> 3) + h * 4 + q;
            *(uint2*)&xtb[g * 32768 + c * 128 + l * 8] = o;
        }
    }
}

// ---------------------------------------------------------------------------
// 2) E = exp(xn@xn^T - 1) fp8, TRIANGLE ONLY (E symmetric): grid 8 x 136
//    tile-pairs (bi<=bj), 128x128 tile, full K=256 unrolled, NO LDS staging
//    (direct coalesced frag loads from xnf), no main-loop barriers.
//    Each tile stored twice (direct + mirror). lsum gets row-sums (bi side)
//    and col-sums (bj side, off-diagonal only).
__global__ __launch_bounds__(512, 4) void k_gemm1(const u8* __restrict__ xnf,
                                                  u8* __restrict__ E,
                                                  float* __restrict__ lsum) {
    __shared__ u8 eCM[128 * 140];   // col-major fp8 tile [col][row], pad 140
    const int wg = blockIdx.x;      // 1088 = 8 x 136; XCD owns one batch
    const int b = wg & 7;
    int idx = wg >> 3, bi = 0;
    while (idx >= 16 - bi) { idx -= 16 - bi; ++bi; }
    const int bj = bi + idx;
    const int t = threadIdx.x;
    const int wave = t >> 6, lane = t & 63;
    const int wr = wave >> 2, wc = wave & 3;   // 2x4 waves, wave tile 64x32
    const int l15 = lane & 15, kl = lane >> 4;
    const u8* xb = xnf + (size_t)b * 524288;
    const int lo8 = kl * 128 + l15 * 8;
    const u8* aB0 = xb + (bi * 8 + wr * 4 + 0) * 4096 + lo8;
    const u8* aB1 = xb + (bi * 8 + wr * 4 + 1) * 4096 + lo8;
    const u8* aB2 = xb + (bi * 8 + wr * 4 + 2) * 4096 + lo8;
    const u8* aB3 = xb + (bi * 8 + wr * 4 + 3) * 4096 + lo8;
    const u8* bB0 = xb + (bj * 8 + wc * 2 + 0) * 4096 + lo8;
    const u8* bB1 = xb + (bj * 8 + wc * 2 + 1) * 4096 + lo8;

    f32x4 acc[4][2] = {};
#pragma unroll
    for (int kk = 0; kk < 8; ++kk) {
        const long a0 = *(const long*)(aB0 + kk * 512);
        const long a1 = *(const long*)(aB1 + kk * 512);
        const long a2 = *(const long*)(aB2 + kk * 512);
        const long a3 = *(const long*)(aB3 + kk * 512);
        const long b0 = *(const long*)(bB0 + kk * 512);
        const long b1 = *(const long*)(bB1 + kk * 512);
        acc[0][0] = __builtin_amdgcn_mfma_f32_16x16x32_fp8_fp8(a0, b0, acc[0][0], 0, 0, 0);
        acc[0][1] = __builtin_amdgcn_mfma_f32_16x16x32_fp8_fp8(a0, b1, acc[0][1], 0, 0, 0);
        acc[1][0] = __builtin_amdgcn_mfma_f32_16x16x32_fp8_fp8(a1, b0, acc[1][0], 0, 0, 0);
        acc[1][1] = __builtin_amdgcn_mfma_f32_16x16x32_fp8_fp8(a1, b1, acc[1][1], 0, 0, 0);
        acc[2][0] = __builtin_amdgcn_mfma_f32_16x16x32_fp8_fp8(a2, b0, acc[2][0], 0, 0, 0);
        acc[2][1] = __builtin_amdgcn_mfma_f32_16x16x32_fp8_fp8(a2, b1, acc[2][1], 0, 0, 0);
        acc[3][0] = __builtin_amdgcn_mfma_f32_16x16x32_fp8_fp8(a3, b0, acc[3][0], 0, 0, 0);
        acc[3][1] = __builtin_amdgcn_mfma_f32_16x16x32_fp8_fp8(a3, b1, acc[3][1], 0, 0, 0);
    }
    // epilogue: e = exp(s-1); row-sum + col-sum atomics; fp8 quads -> eCM.
    float cs[2] = {0.f, 0.f};
#pragma unroll
    for (int i = 0; i < 4; ++i) {
        float rs[4] = {0.f, 0.f, 0.f, 0.f};
#pragma unroll
        for (int j = 0; j < 2; ++j) {
            const int col = wc * 32 + j * 16 + l15;
            const float e0 = __expf(acc[i][j][0] - 1.0f);
            const float e1 = __expf(acc[i][j][1] - 1.0f);
            const float e2 = __expf(acc[i][j][2] - 1.0f);
            const float e3 = __expf(acc[i][j][3] - 1.0f);
            rs[0] += e0; rs[1] += e1; rs[2] += e2; rs[3] += e3;
            cs[j] += e0 + e1 + e2 + e3;
            *(u32*)&eCM[col * 140 + wr * 64 + i * 16 + kl * 4] = pk4(e0, e1, e2, e3);
        }
#pragma unroll
        for (int r = 0; r < 4; ++r) {
#pragma unroll
            for (int m = 1; m < 16; m <<= 1) rs[r] += __shfl_xor(rs[r], m, 64);
            if (l15 == 0)
                atomicAdd(&lsum[b * Nv + bi * 128 + wr * 64 + i * 16 + kl * 4 + r], rs[r]);
        }
    }
    if (bi != bj) {
#pragma unroll
        for (int j = 0; j < 2; ++j) {
            float c = cs[j];
            c += __shfl_xor(c, 16, 64);
            c += __shfl_xor(c, 32, 64);
            if (kl == 0)
                atomicAdd(&lsum[b * Nv + bj * 128 + wc * 32 + j * 16 + l15], c);
        }
    }
    __syncthreads();
    u8* Eb = E + (size_t)b * Nv * Nv;
    // mirror store (coalesced): E[bj*128+c][bi*128 + 0..127] from eCM rows.
    {
        const int c = t >> 2, q = t & 3;
        u32 w[8];
#pragma unroll
        for (int i = 0; i < 8; ++i) w[i] = *(const u32*)&eCM[c * 140 + q * 32 + i * 4];
        uint4 o0 = {w[0], w[1], w[2], w[3]};
        uint4 o1 = {w[4], w[5], w[6], w[7]};
        u8* dst = &Eb[(size_t)(bj * 128 + c) * Nv + bi * 128 + q * 32];
        *(uint4*)dst = o0;
        *(uint4*)(dst + 16) = o1;
    }
    // direct store (off-diagonal): 4x4 byte transpose in registers.
    if (bi != bj) {
        const int rq = t >> 4;            // 0..31 row-quad
#pragma unroll
        for (int it = 0; it < 2; ++it) {
            const int cq = (t & 15) + it * 16;   // 0..31 col-quad
            u32 w0 = *(const u32*)&eCM[(cq * 4 + 0) * 140 + rq * 4];
            u32 w1 = *(const u32*)&eCM[(cq * 4 + 1) * 140 + rq * 4];
            u32 w2 = *(const u32*)&eCM[(cq * 4 + 2) * 140 + rq * 4];
            u32 w3 = *(const u32*)&eCM[(cq * 4 + 3) * 140 + rq * 4];
#pragma unroll
            for (int r = 0; r < 4; ++r) {
                const u32 o = ((w0 >> (8 * r)) & 0xFFu) |
                              (((w1 >> (8 * r)) & 0xFFu) << 8) |
                              (((w2 >> (8 * r)) & 0xFFu) << 16) |
                              (((w3 >> (8 * r)) & 0xFFu) << 24);
                *(u32*)&Eb[(size_t)(bi * 128 + rq * 4 + r) * Nv + bj * 128 + cq * 4] = o;
            }
        }
    }
}

// ---------------------------------------------------------------------------
// 3) x_neg = P @ x, P[n,m] = E[n,m]*(PSCALE/l_n + PSCALE/l_m) built per-kt in
//    LDS (pad-152, conflict-free b64 frags). B-frags DIRECT from xTf (frag-
//    ordered, L2-resident, coalesced — no Xs staging). BK=128, one barrier/kt.
//    Fused: out = LayerNorm(x - OSC*acc)*gamma + beta.
//    Block 64 rows x 256 cols, 8 waves (2x4), wave tile 32x64.
__global__ __launch_bounds__(512) void k_gemm2ln(const u8* __restrict__ E,
                                                 const float* __restrict__ lsum,
                                                 const u8* __restrict__ xTf,
                                                 const float* __restrict__ x,
                                                 const float* __restrict__ gamma,
                                                 const float* __restrict__ beta,
                                                 float* __restrict__ out) {
    __shared__ u8 Ps[2][64 * 152];    // 19 KB, pad 152 (8B-aligned rows)
    __shared__ float rlv[Nv];         // 8 KB: PSCALE / l_m
    __shared__ float red[64][4][2];   // 2 KB
    const int wg = blockIdx.x;        // 256: XCD owns one batch
    const int swz = (wg & 7) * 32 + (wg >> 3);
    const int b = swz >> 5, bi = swz & 31;
    const int t = threadIdx.x;
    const int wave = t >> 6, lane = t & 63;
    const int wr = wave >> 2, wc = wave & 3;
    const int l15 = lane & 15, kl = lane >> 4;
    const int srow = t >> 3, s8 = t & 7;
    const float* lsb = lsum + (size_t)b * Nv;
    const u8* Erow = E + ((size_t)b * Nv + bi * 64 + srow) * Nv + s8 * 16;
    const u8* xtb = xTf + (size_t)b * 524288;
    float linv_n;

#pragma unroll
    for (int q = 0; q < 4; ++q) {
        const int m = q * 512 + t;
        rlv[m] = PSCALE * __builtin_amdgcn_rcpf(lsb[m]);
    }
    // B-frag bases: g = wc*4 + j
    const u8* bB[4];
#pragma unroll
    for (int j = 0; j < 4; ++j)
        bB[j] = xtb + (wc * 4 + j) * 32768 + kl * 128 + l15 * 8;

    auto wstore = [&](u8* pbuf, uint4 ev, int k0) {
        const float* rp = &rlv[k0 + s8 * 16];
        const float4 r0 = *(const float4*)(rp);
        const float4 r1 = *(const float4*)(rp + 4);
        const float4 r2 = *(const float4*)(rp + 8);
        const float4 r3 = *(const float4*)(rp + 12);
        const u32 o0 = pk4(__builtin_amdgcn_cvt_f32_fp8(ev.x, 0) * (linv_n + r0.x),
                           __builtin_amdgcn_cvt_f32_fp8(ev.x, 1) * (linv_n + r0.y),
                           __builtin_amdgcn_cvt_f32_fp8(ev.x, 2) * (linv_n + r0.z),
                           __builtin_amdgcn_cvt_f32_fp8(ev.x, 3) * (linv_n + r0.w));
        const u32 o1 = pk4(__builtin_amdgcn_cvt_f32_fp8(ev.y, 0) * (linv_n + r1.x),
                           __builtin_amdgcn_cvt_f32_fp8(ev.y, 1) * (linv_n + r1.y),
                           __builtin_amdgcn_cvt_f32_fp8(ev.y, 2) * (linv_n + r1.z),
                           __builtin_amdgcn_cvt_f32_fp8(ev.y, 3) * (linv_n + r1.w));
        const u32 o2 = pk4(__builtin_amdgcn_cvt_f32_fp8(ev.z, 0) * (linv_n + r2.x),
                           __builtin_amdgcn_cvt_f32_fp8(ev.z, 1) * (linv_n + r2.y),
                           __builtin_amdgcn_cvt_f32_fp8(ev.z, 2) * (linv_n + r2.z),
                           __builtin_amdgcn_cvt_f32_fp8(ev.z, 3) * (linv_n + r2.w));
        const u32 o3 = pk4(__builtin_amdgcn_cvt_f32_fp8(ev.w, 0) * (linv_n + r3.x),
                           __builtin_amdgcn_cvt_f32_fp8(ev.w, 1) * (linv_n + r3.y),
                           __builtin_amdgcn_cvt_f32_fp8(ev.w, 2) * (linv_n + r3.z),
                           __builtin_amdgcn_cvt_f32_fp8(ev.w, 3) * (linv_n + r3.w));
        uint2 lo = {o0, o1}, hi = {o2, o3};
        *(uint2*)(pbuf + srow * 152 + s8 * 16) = lo;
        *(uint2*)(pbuf + srow * 152 + s8 * 16 + 8) = hi;
    };

    uint4 ev = *(const uint4*)(Erow);          // kt=0 chunk
    __syncthreads();                           // rlv ready
    linv_n = rlv[bi * 64 + srow];
    wstore(Ps[0], ev, 0);
    ev = *(const uint4*)(Erow + 128);          // kt=1 chunk
    __syncthreads();                           // Ps[0] ready

    const int aoff0 = (wr * 32 + l15) * 152 + kl * 8;
    const int aoff1 = aoff0 + 16 * 152;
    f32x4 acc[2][4] = {};
    int cur = 0;
    for (int kt = 0; kt < 16; ++kt) {
        const u8* pc = Ps[cur];
#pragma unroll
        for (int kk = 0; kk < 4; ++kk) {
            const long a0 = *(const long*)(pc + aoff0 + kk * 32);
            const long a1 = *(const long*)(pc + aoff1 + kk * 32);
            const long b0 = *(const long*)(bB[0] + kt * 2048 + kk * 512);
            const long b1 = *(const long*)(bB[1] + kt * 2048 + kk * 512);
            const long b2 = *(const long*)(bB[2] + kt * 2048 + kk * 512);
            const long b3 = *(const long*)(bB[3] + kt * 2048 + kk * 512);
            acc[0][0] = __builtin_amdgcn_mfma_f32_16x16x32_fp8_fp8(a0, b0, acc[0][0], 0, 0, 0);
            acc[0][1] = __builtin_amdgcn_mfma_f32_16x16x32_fp8_fp8(a0, b1, acc[0][1], 0, 0, 0);
            acc[0][2] = __builtin_amdgcn_mfma_f32_16x16x32_fp8_fp8(a0, b2, acc[0][2], 0, 0, 0);
            acc[0][3] = __builtin_amdgcn_mfma_f32_16x16x32_fp8_fp8(a0, b3, acc[0][3], 0, 0, 0);
            acc[1][0] = __builtin_amdgcn_mfma_f32_16x16x32_fp8_fp8(a1, b0, acc[1][0], 0, 0, 0);
            acc[1][1] = __builtin_amdgcn_mfma_f32_16x16x32_fp8_fp8(a1, b1, acc[1][1], 0, 0, 0);
            acc[1][2] = __builtin_amdgcn_mfma_f32_16x16x32_fp8_fp8(a1, b2, acc[1][2], 0, 0, 0);
            acc[1][3] = __builtin_amdgcn_mfma_f32_16x16x32_fp8_fp8(a1, b3, acc[1][3], 0, 0, 0);
        }
        if (kt < 15) {
            wstore(Ps[cur ^ 1], ev, (kt + 1) * 128);
            if (kt < 14) ev = *(const uint4*)(Erow + (kt + 2) * 128);
        }
        __syncthreads();
        cur ^= 1;
    }
    // epilogue: v = x - OSC*acc, LN across the 4 column-waves.
    const float* xb = x + ((size_t)b * Nv + bi * 64) * Dv;
    float tv[2][4][4];
#pragma unroll
    for (int i = 0; i < 2; ++i) {
#pragma unroll
        for (int r = 0; r < 4; ++r) {
            const int rr = wr * 32 + i * 16 + kl * 4 + r;
            float s1 = 0.f, s2 = 0.f;
#pragma unroll
            for (int j = 0; j < 4; ++j) {
                const int cc = wc * 64 + j * 16 + l15;
                const float v = xb[(size_t)rr * Dv + cc] - OSC * acc[i][j][r];
                tv[i][j][r] = v;
                s1 += v; s2 += v * v;
            }
#pragma unroll
            for (int m = 1; m < 16; m <<= 1) {
                s1 += __shfl_xor(s1, m, 64);
                s2 += __shfl_xor(s2, m, 64);
            }
            if (l15 == 0) { red[rr][wc][0] = s1; red[rr][wc][1] = s2; }
        }
    }
    __syncthreads();
#pragma unroll
    for (int i = 0; i < 2; ++i) {
#pragma unroll
        for (int r = 0; r < 4; ++r) {
            const int rr = wr * 32 + i * 16 + kl * 4 + r;
            const float s1 = red[rr][0][0] + red[rr][1][0] + red[rr][2][0] + red[rr][3][0];
            const float s2 = red[rr][0][1] + red[rr][1][1] + red[rr][2][1] + red[rr][3][1];
            const float mu = s1 * (1.0f / Dv);
            const float var = s2 * (1.0f / Dv) - mu * mu;
            const float rstd = rsqrtf(var + LN_EPS);
#pragma unroll
            for (int j = 0; j < 4; ++j) {
                const int cc = wc * 64 + j * 16 + l15;
                out[((size_t)b * Nv + bi * 64 + rr) * Dv + cc] =
                    (tv[i][j][r] - mu) * rstd * gamma[cc] + beta[cc];
            }
        }
    }
}

// ---------------------------------------------------------------------------
extern "C" void kernel_launch(void* const* d_in, const int* in_sizes, int n_in,
                              void* d_out, int out_size, void* d_ws, size_t ws_size,
                              hipStream_t stream) {
    const float* x = (const float*)d_in[0];
    const float* gamma = (const float*)d_in[1];
    const float* beta = (const float*)d_in[2];
    float* out = (float*)d_out;
    char* ws = (char*)d_ws;
    u8* xnf = (u8*)ws;                        // 4.2 MB (fragment-ordered)
    u8* xTf = (u8*)(ws + 4194304);            // 4.2 MB (fragment-ordered)
    float* lsum = (float*)(ws + 8388608);     // 64 KB
    u8* E = (u8*)(ws + 8454144);              // 33.5 MB fp8, row-major

    k_prepT<<<Bv * (Nv / 64), 512, 0, stream>>>(x, xnf, xTf, lsum);
    k_gemm1<<<Bv * 136, 512, 0, stream>>>(xnf, E, lsum);
    k_gemm2ln<<<Bv * (Nv / 64), 512, 0, stream>>>(E, lsum, xTf, x, gamma, beta, out);
}

// Round 9
// 77.899 us; speedup vs baseline: 1.2155x; 1.1314x over previous
//
#include <hip/hip_runtime.h>

namespace {
constexpr int Bv = 8;
constexpr int Nv = 2048;
constexpr int Dv = 256;
constexpr float SCALE = 0.1f;
constexpr float PSCALE = 256.0f;          // P quant scale (fp8 normal range)
constexpr float OSC = SCALE / PSCALE;     // epilogue un-scale
constexpr float LN_EPS = 1e-6f;
constexpr float NORM_EPS = 1e-12f;
}

typedef unsigned char u8;
typedef unsigned int u32;
typedef __attribute__((ext_vector_type(4))) float f32x4;

// global -> LDS direct DMA, 16B/lane. lds base wave-uniform; HW adds lane*16.
__device__ __forceinline__ void gll16(const void* g, void* l) {
    __builtin_amdgcn_global_load_lds(
        (__attribute__((address_space(1))) void*)(uintptr_t)g,
        (__attribute__((address_space(3))) void*)(uintptr_t)l, 16, 0, 0);
}
// pack 4 f32 -> 4 fp8 e4m3 bytes
__device__ __forceinline__ u32 pk4(float a, float b, float c, float d) {
    u32 w = __builtin_amdgcn_cvt_pk_fp8_f32(a, b, 0, false);
    return __builtin_amdgcn_cvt_pk_fp8_f32(c, d, w, true);
}

// ---------------------------------------------------------------------------
// 1) Fused prep. Outputs: xn8 row-major fp8 (L2-normalized rows) and
//    xTf frag-ordered fp8 (raw x transposed): [g=d/16][c=n/8][l=d%16][8B].
//    Block = 64 n-rows x 256 d.
__global__ __launch_bounds__(512) void k_prepT(const float* __restrict__ x,
                                               u8* __restrict__ xn8,
                                               u8* __restrict__ xTf) {
    __shared__ u8 lt[64][272];   // raw-x fp8 [n_local][d]
    const int b = blockIdx.x >> 5;
    const int n0 = (blockIdx.x & 31) * 64;
    const int t = threadIdx.x;
    const int r = t >> 3, c0 = (t & 7) * 32;
    const float* xr = x + ((size_t)b * Nv + n0 + r) * Dv + c0;
    float4 v[8];
    float ss = 0.f;
#pragma unroll
    for (int i = 0; i < 8; ++i) {
        v[i] = ((const float4*)xr)[i];
        ss += v[i].x * v[i].x + v[i].y * v[i].y + v[i].z * v[i].z + v[i].w * v[i].w;
    }
#pragma unroll
    for (int m = 1; m < 8; m <<= 1) ss += __shfl_xor(ss, m, 64);
    const float inv = 1.0f / fmaxf(sqrtf(ss), NORM_EPS);
    u32 wn[8];
#pragma unroll
    for (int i = 0; i < 8; ++i) {
        wn[i] = pk4(v[i].x * inv, v[i].y * inv, v[i].z * inv, v[i].w * inv);
        *(u32*)&lt[r][c0 + i * 4] = pk4(v[i].x, v[i].y, v[i].z, v[i].w);
    }
    {   // xn8 row-major
        uint4 o0 = {wn[0], wn[1], wn[2], wn[3]};
        uint4 o1 = {wn[4], wn[5], wn[6], wn[7]};
        u8* xnr = xn8 + ((size_t)b * Nv + n0 + r) * Dv + c0;
        *(uint4*)xnr = o0;
        *(uint4*)(xnr + 16) = o1;
    }
    __syncthreads();
    {   // xTf frag-ordered: thread handles d = t>>1, n-half h = t&1
        u8* xtb = xTf + (size_t)b * 524288;
        const int d = t >> 1, h = t & 1;
        const int g = d >> 4, l = d & 15;
#pragma unroll
        for (int q = 0; q < 4; ++q) {
            const int nb = h * 32 + q * 8;
            u32 lo = (u32)lt[nb][d] | ((u32)lt[nb + 1][d] << 8) |
                     ((u32)lt[nb + 2][d] << 16) | ((u32)lt[nb + 3][d] << 24);
            u32 hi = (u32)lt[nb + 4][d] | ((u32)lt[nb + 5][d] << 8) |
                     ((u32)lt[nb + 6][d] << 16) | ((u32)lt[nb + 7][d] << 24);
            uint2 o = {lo, hi};
            const int c = (n0 >> 3) + h * 4 + q;
            *(uint2*)&xtb[g * 32768 + c * 128 + l * 8] = o;
        }
    }
}

// ---------------------------------------------------------------------------
// 2) E = exp(xn@xn^T - 1) fp8, row-panel blocks: 32 rows x ALL 2048 cols.
//    A-frags in registers; B gll16-staged, 256B rows, slot^(row&15) swizzle
//    (conflict-free), dbuf over 16 chunks of 128 cols. lsum = plain write
//    (block owns full rows — NO atomics). E stored via col-major LDS restage
//    (covers E[m][panel-cols], all m -> full matrix across blocks).
__global__ __launch_bounds__(512, 4) void k_gemm1(const u8* __restrict__ xn8,
                                                  u8* __restrict__ E,
                                                  float* __restrict__ lsum) {
    __shared__ u8 Bs[2][128 * 256];   // 2 x 32 KB
    __shared__ u8 eS[2][128 * 40];    // [m-col][32 n + pad8], 2 x 5 KB
    __shared__ float red[32][4];
    const int wg = blockIdx.x;        // 512: XCD owns one batch
    const int b = wg & 7, bi = wg >> 3;            // bi 0..63 (32-row panel)
    const int t = threadIdx.x;
    const int wave = t >> 6, lane = t & 63;
    const int wr = wave >> 2, wc = wave & 3;       // wave tile 16r x 32c
    const int l15 = lane & 15, kl = lane >> 4;
    const u8* xb = xn8 + (size_t)b * (Nv * Dv);

    auto stageB = [&](int buf, int ch) {   // 128 rows x 256B
#pragma unroll
        for (int c = 0; c < 4; ++c) {
            const int row = wave * 16 + c * 4 + (lane >> 4);
            const int slot = (lane & 15) ^ (row & 15);
            gll16(xb + (size_t)(ch * 128 + row) * Dv + slot * 16,
                  Bs[buf] + wave * 4096 + c * 1024);
        }
    };
    auto bfrag = [&](const u8* base, int row, int kk) -> long {
        const int slot = kk * 2 + (kl >> 1);
        return *(const long*)(base + row * 256 +
                              ((slot ^ (row & 15)) << 4) + ((kl & 1) << 3));
    };

    const int ch0 = bi >> 2;   // chunk containing this panel's own rows
    stageB(0, ch0);
    __syncthreads();
    long af[8];
    {
        const int arow = (bi & 3) * 32 + wr * 16 + l15;
#pragma unroll
        for (int kk = 0; kk < 8; ++kk) af[kk] = bfrag(Bs[0], arow, kk);
    }
    float rs[4] = {0.f, 0.f, 0.f, 0.f};
    u8* Eb = E + (size_t)b * Nv * Nv;
    int cur = 0;
    for (int cc = 0; cc < 16; ++cc) {
        const int ch = (ch0 + cc) & 15;
        if (cc < 15) stageB(cur ^ 1, (ch0 + cc + 1) & 15);
        f32x4 acc[2] = {};
#pragma unroll
        for (int kk = 0; kk < 8; ++kk) {
            const long b0 = bfrag(Bs[cur], wc * 32 + l15, kk);
            const long b1 = bfrag(Bs[cur], wc * 32 + 16 + l15, kk);
            acc[0] = __builtin_amdgcn_mfma_f32_16x16x32_fp8_fp8(af[kk], b0, acc[0], 0, 0, 0);
            acc[1] = __builtin_amdgcn_mfma_f32_16x16x32_fp8_fp8(af[kk], b1, acc[1], 0, 0, 0);
        }
#pragma unroll
        for (int j = 0; j < 2; ++j) {
            const int col = wc * 32 + j * 16 + l15;   // m within chunk
            const float e0 = __expf(acc[j][0] - 1.0f);
            const float e1 = __expf(acc[j][1] - 1.0f);
            const float e2 = __expf(acc[j][2] - 1.0f);
            const float e3 = __expf(acc[j][3] - 1.0f);
            rs[0] += e0; rs[1] += e1; rs[2] += e2; rs[3] += e3;
            *(u32*)&eS[cur][col * 40 + wr * 16 + kl * 4] = pk4(e0, e1, e2, e3);
        }
        __syncthreads();   // Bs[cur^1] staged; eS[cur] complete
        {   // store: E[m = ch*128 + c][bi*32 + 0..31], 8B per thread
            const int c = t >> 2, sg = t & 3;
            *(uint2*)&Eb[(size_t)(ch * 128 + c) * Nv + bi * 32 + sg * 8] =
                *(const uint2*)&eS[cur][c * 40 + sg * 8];
        }
        cur ^= 1;
    }
    // lsum: reduce rs over 16 cols (l15) then over 4 wc-waves; plain store.
#pragma unroll
    for (int r = 0; r < 4; ++r) {
        float v = rs[r];
#pragma unroll
        for (int m = 1; m < 16; m <<= 1) v += __shfl_xor(v, m, 64);
        if (l15 == 0) red[wr * 16 + kl * 4 + r][wc] = v;
    }
    __syncthreads();
    if (t < 32)
        lsum[b * Nv + bi * 32 + t] = red[t][0] + red[t][1] + red[t][2] + red[t][3];
}

// ---------------------------------------------------------------------------
// 3) x_neg = P @ x, P[n,m] = E[n,m]*(PSCALE/l_n + PSCALE/l_m) built per-kt in
//    LDS (pad-152 rows, conflict-free b64 frags). B-frags direct from xTf
//    (frag-ordered, L2-resident). BK=128, depth-2 E prefetch, one barrier/kt.
//    Fused: out = LayerNorm(x - OSC*acc)*gamma + beta.
//    Block 32 rows x 256 cols, 8 waves (2x4), wave tile 16x64. 2 blocks/CU.
__global__ __launch_bounds__(512) void k_gemm2ln(const u8* __restrict__ E,
                                                 const float* __restrict__ lsum,
                                                 const u8* __restrict__ xTf,
                                                 const float* __restrict__ x,
                                                 const float* __restrict__ gamma,
                                                 const float* __restrict__ beta,
                                                 float* __restrict__ out) {
    __shared__ u8 Ps[2][32 * 152];    // 9.5 KB
    __shared__ float rlv[Nv];         // 8 KB: PSCALE / l_m
    __shared__ float red[32][4][2];   // 1 KB
    const int wg = blockIdx.x;        // 512: XCD owns one batch
    const int swz = (wg & 7) * 64 + (wg >> 3);
    const int b = swz >> 6, bi = swz & 63;         // 32-row panel
    const int t = threadIdx.x;
    const int wave = t >> 6, lane = t & 63;
    const int wr = wave >> 2, wc = wave & 3;       // wave tile 16r x 64c
    const int l15 = lane & 15, kl = lane >> 4;
    const int srow = t >> 4, s16 = t & 15;         // staging: 16 thr/row
    const float* lsb = lsum + (size_t)b * Nv;
    const u8* Erow = E + ((size_t)b * Nv + bi * 32 + srow) * Nv + s16 * 8;
    const u8* xtb = xTf + (size_t)b * 524288;
    float linv_n;

#pragma unroll
    for (int q = 0; q < 4; ++q) {
        const int m = q * 512 + t;
        rlv[m] = PSCALE * __builtin_amdgcn_rcpf(lsb[m]);
    }
    const u8* bB[4];
#pragma unroll
    for (int j = 0; j < 4; ++j)
        bB[j] = xtb + (wc * 4 + j) * 32768 + kl * 128 + l15 * 8;

    auto wstore = [&](u8* pbuf, uint2 ev, int k0) {
        const float* rp = &rlv[k0 + s16 * 8];
        const float4 r0 = *(const float4*)(rp);
        const float4 r1 = *(const float4*)(rp + 4);
        const u32 o0 = pk4(__builtin_amdgcn_cvt_f32_fp8(ev.x, 0) * (linv_n + r0.x),
                           __builtin_amdgcn_cvt_f32_fp8(ev.x, 1) * (linv_n + r0.y),
                           __builtin_amdgcn_cvt_f32_fp8(ev.x, 2) * (linv_n + r0.z),
                           __builtin_amdgcn_cvt_f32_fp8(ev.x, 3) * (linv_n + r0.w));
        const u32 o1 = pk4(__builtin_amdgcn_cvt_f32_fp8(ev.y, 0) * (linv_n + r1.x),
                           __builtin_amdgcn_cvt_f32_fp8(ev.y, 1) * (linv_n + r1.y),
                           __builtin_amdgcn_cvt_f32_fp8(ev.y, 2) * (linv_n + r1.z),
                           __builtin_amdgcn_cvt_f32_fp8(ev.y, 3) * (linv_n + r1.w));
        uint2 o = {o0, o1};
        *(uint2*)(pbuf + srow * 152 + s16 * 8) = o;
    };

    uint2 evB = *(const uint2*)(Erow);
    __syncthreads();                   // rlv ready
    linv_n = rlv[bi * 32 + srow];
    wstore(Ps[0], evB, 0);
    evB = *(const uint2*)(Erow + 128);
    uint2 evC = *(const uint2*)(Erow + 256);
    __syncthreads();                   // Ps[0] ready

    const int aoff = (wr * 16 + l15) * 152 + kl * 8;
    f32x4 acc[4] = {};
    int cur = 0;
    for (int kt = 0; kt < 16; ++kt) {
        const u8* pc = Ps[cur];
#pragma unroll
        for (int kk = 0; kk < 4; ++kk) {
            const long a0 = *(const long*)(pc + aoff + kk * 32);
            const long b0 = *(const long*)(bB[0] + kt * 2048 + kk * 512);
            const long b1 = *(const long*)(bB[1] + kt * 2048 + kk * 512);
            const long b2 = *(const long*)(bB[2] + kt * 2048 + kk * 512);
            const long b3 = *(const long*)(bB[3] + kt * 2048 + kk * 512);
            acc[0] = __builtin_amdgcn_mfma_f32_16x16x32_fp8_fp8(a0, b0, acc[0], 0, 0, 0);
            acc[1] = __builtin_amdgcn_mfma_f32_16x16x32_fp8_fp8(a0, b1, acc[1], 0, 0, 0);
            acc[2] = __builtin_amdgcn_mfma_f32_16x16x32_fp8_fp8(a0, b2, acc[2], 0, 0, 0);
            acc[3] = __builtin_amdgcn_mfma_f32_16x16x32_fp8_fp8(a0, b3, acc[3], 0, 0, 0);
        }
        if (kt < 15) {
            wstore(Ps[cur ^ 1], evB, (kt + 1) * 128);
            evB = evC;
            if (kt < 14) evC = *(const uint2*)(Erow + (kt + 2) * 128);
        }
        __syncthreads();
        cur ^= 1;
    }
    // epilogue: v = x - OSC*acc, LN across the 4 column-waves.
    const float* xb = x + ((size_t)b * Nv + bi * 32) * Dv;
    float tv[4][4];
#pragma unroll
    for (int r = 0; r < 4; ++r) {
        const int rr = wr * 16 + kl * 4 + r;
        float s1 = 0.f, s2 = 0.f;
#pragma unroll
        for (int j = 0; j < 4; ++j) {
            const int cc = wc * 64 + j * 16 + l15;
            const float v = xb[(size_t)rr * Dv + cc] - OSC * acc[j][r];
            tv[j][r] = v;
            s1 += v; s2 += v * v;
        }
#pragma unroll
        for (int m = 1; m < 16; m <<= 1) {
            s1 += __shfl_xor(s1, m, 64);
            s2 += __shfl_xor(s2, m, 64);
        }
        if (l15 == 0) { red[rr][wc][0] = s1; red[rr][wc][1] = s2; }
    }
    __syncthreads();
#pragma unroll
    for (int r = 0; r < 4; ++r) {
        const int rr = wr * 16 + kl * 4 + r;
        const float s1 = red[rr][0][0] + red[rr][1][0] + red[rr][2][0] + red[rr][3][0];
        const float s2 = red[rr][0][1] + red[rr][1][1] + red[rr][2][1] + red[rr][3][1];
        const float mu = s1 * (1.0f / Dv);
        const float var = s2 * (1.0f / Dv) - mu * mu;
        const float rstd = rsqrtf(var + LN_EPS);
#pragma unroll
        for (int j = 0; j < 4; ++j) {
            const int cc = wc * 64 + j * 16 + l15;
            out[((size_t)b * Nv + bi * 32 + rr) * Dv + cc] =
                (tv[j][r] - mu) * rstd * gamma[cc] + beta[cc];
        }
    }
}

// ---------------------------------------------------------------------------
extern "C" void kernel_launch(void* const* d_in, const int* in_sizes, int n_in,
                              void* d_out, int out_size, void* d_ws, size_t ws_size,
                              hipStream_t stream) {
    const float* x = (const float*)d_in[0];
    const float* gamma = (const float*)d_in[1];
    const float* beta = (const float*)d_in[2];
    float* out = (float*)d_out;
    char* ws = (char*)d_ws;
    u8* xn8 = (u8*)ws;                        // 4.2 MB row-major fp8
    u8* xTf = (u8*)(ws + 4194304);            // 4.2 MB frag-ordered fp8
    float* lsum = (float*)(ws + 8388608);     // 64 KB
    u8* E = (u8*)(ws + 8454144);              // 33.5 MB fp8, row-major

    k_prepT<<<Bv * (Nv / 64), 512, 0, stream>>>(x, xn8, xTf);
    k_gemm1<<<Bv * (Nv / 32), 512, 0, stream>>>(xn8, E, lsum);
    k_gemm2ln<<<Bv * (Nv / 32), 512, 0, stream>>>(E, lsum, xTf, x, gamma, beta, out);
}

// Round 10
// 66.085 us; speedup vs baseline: 1.4328x; 1.1788x over previous
//
#include <hip/hip_runtime.h>

namespace {
constexpr int Bv = 8;
constexpr int Nv = 2048;
constexpr int Dv = 256;
constexpr float SCALE = 0.1f;
constexpr float PSCALE = 256.0f;          // P quant scale (fp8 normal range)
constexpr float OSC = SCALE / PSCALE;     // epilogue un-scale
constexpr float LN_EPS = 1e-6f;
constexpr float NORM_EPS = 1e-12f;
}

typedef unsigned char u8;
typedef unsigned int u32;
typedef __attribute__((ext_vector_type(4))) float f32x4;

// global -> LDS direct DMA, 16B/lane. lds base wave-uniform; HW adds lane*16.
__device__ __forceinline__ void gll16(const void* g, void* l) {
    __builtin_amdgcn_global_load_lds(
        (__attribute__((address_space(1))) void*)(uintptr_t)g,
        (__attribute__((address_space(3))) void*)(uintptr_t)l, 16, 0, 0);
}
// pack 4 f32 -> 4 fp8 e4m3 bytes
__device__ __forceinline__ u32 pk4(float a, float b, float c, float d) {
    u32 w = __builtin_amdgcn_cvt_pk_fp8_f32(a, b, 0, false);
    return __builtin_amdgcn_cvt_pk_fp8_f32(c, d, w, true);
}

// ---------------------------------------------------------------------------
// 1) Fused prep. Outputs: xn8 row-major fp8 (L2-normalized rows) and
//    xT8 row-major fp8 (raw x transposed, [b][d][n]). Block = 64 rows x 256 d.
__global__ __launch_bounds__(512) void k_prepT(const float* __restrict__ x,
                                               u8* __restrict__ xn8,
                                               u8* __restrict__ xT8) {
    __shared__ u8 lt[64][272];   // raw-x fp8 [n_local][d]
    const int b = blockIdx.x >> 5;
    const int n0 = (blockIdx.x & 31) * 64;
    const int t = threadIdx.x;
    const int r = t >> 3, c0 = (t & 7) * 32;
    const float* xr = x + ((size_t)b * Nv + n0 + r) * Dv + c0;
    float4 v[8];
    float ss = 0.f;
#pragma unroll
    for (int i = 0; i < 8; ++i) {
        v[i] = ((const float4*)xr)[i];
        ss += v[i].x * v[i].x + v[i].y * v[i].y + v[i].z * v[i].z + v[i].w * v[i].w;
    }
#pragma unroll
    for (int m = 1; m < 8; m <<= 1) ss += __shfl_xor(ss, m, 64);
    const float inv = 1.0f / fmaxf(sqrtf(ss), NORM_EPS);
    u32 wn[8];
#pragma unroll
    for (int i = 0; i < 8; ++i) {
        wn[i] = pk4(v[i].x * inv, v[i].y * inv, v[i].z * inv, v[i].w * inv);
        *(u32*)&lt[r][c0 + i * 4] = pk4(v[i].x, v[i].y, v[i].z, v[i].w);
    }
    {   // xn8 row-major
        uint4 o0 = {wn[0], wn[1], wn[2], wn[3]};
        uint4 o1 = {wn[4], wn[5], wn[6], wn[7]};
        u8* xnr = xn8 + ((size_t)b * Nv + n0 + r) * Dv + c0;
        *(uint4*)xnr = o0;
        *(uint4*)(xnr + 16) = o1;
    }
    __syncthreads();
    {   // xT8 row-major [d][n]: thread handles d = t>>1, n-half h = t&1
        const int d = t >> 1, h = t & 1;
        u32 w2[8];
#pragma unroll
        for (int q = 0; q < 8; ++q) {
            const int nb = h * 32 + q * 4;
            w2[q] = (u32)lt[nb][d] | ((u32)lt[nb + 1][d] << 8) |
                    ((u32)lt[nb + 2][d] << 16) | ((u32)lt[nb + 3][d] << 24);
        }
        uint4 p0 = {w2[0], w2[1], w2[2], w2[3]};
        uint4 p1 = {w2[4], w2[5], w2[6], w2[7]};
        u8* xtr = xT8 + ((size_t)b * Dv + d) * Nv + n0 + h * 32;
        *(uint4*)xtr = p0;
        *(uint4*)(xtr + 16) = p1;
    }
}

// ---------------------------------------------------------------------------
// 2) E = exp(xn@xn^T - 1) fp8, row-panel blocks: 32 rows x ALL 2048 cols.
//    A-frags in registers; B gll16-staged, 256B rows, slot^(row&15) swizzle,
//    dbuf over 16 chunks of 128 cols. Writes rl[n] = PSCALE/l_n directly
//    (block owns full rows — no atomics). E stored via col-major LDS restage.
__global__ __launch_bounds__(512, 4) void k_gemm1(const u8* __restrict__ xn8,
                                                  u8* __restrict__ E,
                                                  float* __restrict__ rl) {
    __shared__ u8 Bs[2][128 * 256];   // 2 x 32 KB
    __shared__ u8 eS[2][128 * 40];    // [m-col][32 n + pad8], 2 x 5 KB
    __shared__ float red[32][4];
    const int wg = blockIdx.x;        // 512: XCD owns one batch
    const int b = wg & 7, bi = wg >> 3;            // bi 0..63 (32-row panel)
    const int t = threadIdx.x;
    const int wave = t >> 6, lane = t & 63;
    const int wr = wave >> 2, wc = wave & 3;       // wave tile 16r x 32c
    const int l15 = lane & 15, kl = lane >> 4;
    const u8* xb = xn8 + (size_t)b * (Nv * Dv);

    auto stageB = [&](int buf, int ch) {   // 128 rows x 256B
#pragma unroll
        for (int c = 0; c < 4; ++c) {
            const int row = wave * 16 + c * 4 + (lane >> 4);
            const int slot = (lane & 15) ^ (row & 15);
            gll16(xb + (size_t)(ch * 128 + row) * Dv + slot * 16,
                  Bs[buf] + wave * 4096 + c * 1024);
        }
    };
    auto bfrag = [&](const u8* base, int row, int kk) -> long {
        const int slot = kk * 2 + (kl >> 1);
        return *(const long*)(base + row * 256 +
                              ((slot ^ (row & 15)) << 4) + ((kl & 1) << 3));
    };

    const int ch0 = bi >> 2;   // chunk containing this panel's own rows
    stageB(0, ch0);
    __syncthreads();
    long af[8];
    {
        const int arow = (bi & 3) * 32 + wr * 16 + l15;
#pragma unroll
        for (int kk = 0; kk < 8; ++kk) af[kk] = bfrag(Bs[0], arow, kk);
    }
    float rs[4] = {0.f, 0.f, 0.f, 0.f};
    u8* Eb = E + (size_t)b * Nv * Nv;
    int cur = 0;
    for (int cc = 0; cc < 16; ++cc) {
        const int ch = (ch0 + cc) & 15;
        if (cc < 15) stageB(cur ^ 1, (ch0 + cc + 1) & 15);
        f32x4 acc[2] = {};
#pragma unroll
        for (int kk = 0; kk < 8; ++kk) {
            const long b0 = bfrag(Bs[cur], wc * 32 + l15, kk);
            const long b1 = bfrag(Bs[cur], wc * 32 + 16 + l15, kk);
            acc[0] = __builtin_amdgcn_mfma_f32_16x16x32_fp8_fp8(af[kk], b0, acc[0], 0, 0, 0);
            acc[1] = __builtin_amdgcn_mfma_f32_16x16x32_fp8_fp8(af[kk], b1, acc[1], 0, 0, 0);
        }
#pragma unroll
        for (int j = 0; j < 2; ++j) {
            const int col = wc * 32 + j * 16 + l15;   // m within chunk
            const float e0 = __expf(acc[j][0] - 1.0f);
            const float e1 = __expf(acc[j][1] - 1.0f);
            const float e2 = __expf(acc[j][2] - 1.0f);
            const float e3 = __expf(acc[j][3] - 1.0f);
            rs[0] += e0; rs[1] += e1; rs[2] += e2; rs[3] += e3;
            *(u32*)&eS[cur][col * 40 + wr * 16 + kl * 4] = pk4(e0, e1, e2, e3);
        }
        __syncthreads();   // Bs[cur^1] staged; eS[cur] complete
        {   // store: E[m = ch*128 + c][bi*32 + 0..31], 8B per thread
            const int c = t >> 2, sg = t & 3;
            *(uint2*)&Eb[(size_t)(ch * 128 + c) * Nv + bi * 32 + sg * 8] =
                *(const uint2*)&eS[cur][c * 40 + sg * 8];
        }
        cur ^= 1;
    }
#pragma unroll
    for (int r = 0; r < 4; ++r) {
        float v = rs[r];
#pragma unroll
        for (int m = 1; m < 16; m <<= 1) v += __shfl_xor(v, m, 64);
        if (l15 == 0) red[wr * 16 + kl * 4 + r][wc] = v;
    }
    __syncthreads();
    if (t < 32)
        rl[b * Nv + bi * 32 + t] =
            PSCALE * __builtin_amdgcn_rcpf(red[t][0] + red[t][1] + red[t][2] + red[t][3]);
}

// ---------------------------------------------------------------------------
// 3) x_neg = P @ x, P[n,m] = E[n,m]*(rl_n + rl_m) built per-kt in Ps (stride
//    136 = 17 odd 8B-slots -> conflict-free A-frags). B staged per-kt via
//    gll16 into swizzled LDS (256 d-rows x 128B, slot^(row&7)), dbuf.
//    Wave tile 32x32 (acc[2][2]) so each staged byte feeds 2 MFMAs.
//    Fused: out = LayerNorm(x - OSC*acc)*gamma + beta. 2 blocks/CU.
__global__ __launch_bounds__(512) void k_gemm2ln(const u8* __restrict__ E,
                                                 const float* __restrict__ rl,
                                                 const u8* __restrict__ xT8,
                                                 const float* __restrict__ x,
                                                 const float* __restrict__ gamma,
                                                 const float* __restrict__ beta,
                                                 float* __restrict__ out) {
    __shared__ u8 Bs[2][256 * 128];   // 64 KB
    __shared__ u8 Ps[2][32 * 136];    // 8.5 KB
    __shared__ float red[32][8][2];   // 2 KB
    const int wg = blockIdx.x;        // 512: XCD owns one batch
    const int swz = (wg & 7) * 64 + (wg >> 3);
    const int b = swz >> 6, bi = swz & 63;         // 32-row panel
    const int t = threadIdx.x;
    const int wave = t >> 6, lane = t & 63;
    const int l15 = lane & 15, kl = lane >> 4;
    const int srow = t >> 4, s16 = t & 15;         // P staging: 16 thr/row
    const float* rlb = rl + (size_t)b * Nv;
    const u8* Erow = E + ((size_t)b * Nv + bi * 32 + srow) * Nv + s16 * 8;
    const u8* xtb = xT8 + (size_t)b * 524288;

    auto issueB = [&](int buf, int kt) {   // stage 256 d-rows x 128B
#pragma unroll
        for (int c = 0; c < 4; ++c) {
            const int row = c * 64 + wave * 8 + (lane >> 3);
            const int slot = (lane & 7) ^ (row & 7);
            gll16(xtb + (size_t)row * Nv + kt * 128 + slot * 16,
                  (char*)Bs[buf] + c * 8192 + wave * 1024);
        }
    };
    auto bfragB = [&](const u8* base, int d, int kk) -> long {
        const int s = kk * 2 + (kl >> 1);
        return *(const long*)(base + d * 128 + ((s ^ (d & 7)) << 4) + ((kl & 1) << 3));
    };
    auto afrag = [&](const u8* base, int row, int kk) -> long {
        return *(const long*)(base + row * 136 + kk * 32 + kl * 8);
    };

    const float linv_n = rlb[bi * 32 + srow];
    auto wstore = [&](u8* pbuf, uint2 ev, float4 ra, float4 rb) {
        const u32 o0 = pk4(__builtin_amdgcn_cvt_f32_fp8(ev.x, 0) * (linv_n + ra.x),
                           __builtin_amdgcn_cvt_f32_fp8(ev.x, 1) * (linv_n + ra.y),
                           __builtin_amdgcn_cvt_f32_fp8(ev.x, 2) * (linv_n + ra.z),
                           __builtin_amdgcn_cvt_f32_fp8(ev.x, 3) * (linv_n + ra.w));
        const u32 o1 = pk4(__builtin_amdgcn_cvt_f32_fp8(ev.y, 0) * (linv_n + rb.x),
                           __builtin_amdgcn_cvt_f32_fp8(ev.y, 1) * (linv_n + rb.y),
                           __builtin_amdgcn_cvt_f32_fp8(ev.y, 2) * (linv_n + rb.z),
                           __builtin_amdgcn_cvt_f32_fp8(ev.y, 3) * (linv_n + rb.w));
        uint2 o = {o0, o1};
        *(uint2*)(pbuf + srow * 136 + s16 * 8) = o;
    };

    issueB(0, 0);
    uint2 evB = *(const uint2*)(Erow);
    float4 raB = *(const float4*)&rlb[s16 * 8];
    float4 rbB = *(const float4*)&rlb[s16 * 8 + 4];
    wstore(Ps[0], evB, raB, rbB);
    evB = *(const uint2*)(Erow + 128);
    uint2 evC = *(const uint2*)(Erow + 256);
    raB = *(const float4*)&rlb[128 + s16 * 8];
    rbB = *(const float4*)&rlb[128 + s16 * 8 + 4];
    __syncthreads();                   // Bs[0] (vmcnt drain) + Ps[0] ready

    f32x4 acc[2][2] = {};
    int cur = 0;
    for (int kt = 0; kt < 16; ++kt) {
        if (kt < 15) issueB(cur ^ 1, kt + 1);
#pragma unroll
        for (int kk = 0; kk < 4; ++kk) {
            const long a0 = afrag(Ps[cur], l15, kk);
            const long a1 = afrag(Ps[cur], 16 + l15, kk);
            const long b0 = bfragB(Bs[cur], wave * 32 + l15, kk);
            const long b1 = bfragB(Bs[cur], wave * 32 + 16 + l15, kk);
            acc[0][0] = __builtin_amdgcn_mfma_f32_16x16x32_fp8_fp8(a0, b0, acc[0][0], 0, 0, 0);
            acc[0][1] = __builtin_amdgcn_mfma_f32_16x16x32_fp8_fp8(a0, b1, acc[0][1], 0, 0, 0);
            acc[1][0] = __builtin_amdgcn_mfma_f32_16x16x32_fp8_fp8(a1, b0, acc[1][0], 0, 0, 0);
            acc[1][1] = __builtin_amdgcn_mfma_f32_16x16x32_fp8_fp8(a1, b1, acc[1][1], 0, 0, 0);
        }
        if (kt < 15) {
            wstore(Ps[cur ^ 1], evB, raB, rbB);
            evB = evC;
            if (kt < 14) {
                evC = *(const uint2*)(Erow + (kt + 2) * 128);
                raB = *(const float4*)&rlb[(kt + 1) * 128 + s16 * 8];
                rbB = *(const float4*)&rlb[(kt + 1) * 128 + s16 * 8 + 4];
            }
        }
        __syncthreads();
        cur ^= 1;
    }
    // epilogue: v = x - OSC*acc, LN across the 8 waves (32 cols each).
    const float* xb = x + ((size_t)b * Nv + bi * 32) * Dv;
    float tv[2][2][4];
#pragma unroll
    for (int i = 0; i < 2; ++i) {
#pragma unroll
        for (int r = 0; r < 4; ++r) {
            const int rr = i * 16 + kl * 4 + r;
            float s1 = 0.f, s2 = 0.f;
#pragma unroll
            for (int j = 0; j < 2; ++j) {
                const int cc = wave * 32 + j * 16 + l15;
                const float v = xb[(size_t)rr * Dv + cc] - OSC * acc[i][j][r];
                tv[i][j][r] = v;
                s1 += v; s2 += v * v;
            }
#pragma unroll
            for (int m = 1; m < 16; m <<= 1) {
                s1 += __shfl_xor(s1, m, 64);
                s2 += __shfl_xor(s2, m, 64);
            }
            if (l15 == 0) { red[rr][wave][0] = s1; red[rr][wave][1] = s2; }
        }
    }
    __syncthreads();
#pragma unroll
    for (int i = 0; i < 2; ++i) {
#pragma unroll
        for (int r = 0; r < 4; ++r) {
            const int rr = i * 16 + kl * 4 + r;
            float s1 = 0.f, s2 = 0.f;
#pragma unroll
            for (int w = 0; w < 8; ++w) { s1 += red[rr][w][0]; s2 += red[rr][w][1]; }
            const float mu = s1 * (1.0f / Dv);
            const float var = s2 * (1.0f / Dv) - mu * mu;
            const float rstd = rsqrtf(var + LN_EPS);
#pragma unroll
            for (int j = 0; j < 2; ++j) {
                const int cc = wave * 32 + j * 16 + l15;
                out[((size_t)b * Nv + bi * 32 + rr) * Dv + cc] =
                    (tv[i][j][r] - mu) * rstd * gamma[cc] + beta[cc];
            }
        }
    }
}

// ---------------------------------------------------------------------------
extern "C" void kernel_launch(void* const* d_in, const int* in_sizes, int n_in,
                              void* d_out, int out_size, void* d_ws, size_t ws_size,
                              hipStream_t stream) {
    const float* x = (const float*)d_in[0];
    const float* gamma = (const float*)d_in[1];
    const float* beta = (const float*)d_in[2];
    float* out = (float*)d_out;
    char* ws = (char*)d_ws;
    u8* xn8 = (u8*)ws;                        // 4.2 MB row-major fp8
    u8* xT8 = (u8*)(ws + 4194304);            // 4.2 MB row-major fp8 [d][n]
    float* rl = (float*)(ws + 8388608);       // 64 KB: PSCALE / l_n
    u8* E = (u8*)(ws + 8454144);              // 33.5 MB fp8, row-major

    k_prepT<<<Bv * (Nv / 64), 512, 0, stream>>>(x, xn8, xT8);
    k_gemm1<<<Bv * (Nv / 32), 512, 0, stream>>>(xn8, E, rl);
    k_gemm2ln<<<Bv * (Nv / 32), 512, 0, stream>>>(E, rl, xT8, x, gamma, beta, out);
}